// Round 4
// baseline (208.451 us; speedup 1.0000x reference)
//
#include <hip/hip_runtime.h>
#include <math.h>

// Problem constants (from reference setup_inputs)
#define BB 32
#define TT 750
#define DD 2048
#define CC 20
#define MM 750
#define SS 64
#define MT 64          // gcn m-tile
#define NT 12          // ceil(750/64)
#define TSPLIT 8       // feat t-split
#define TCH 94         // ceil(750/8)

#define GCN_BLOCKS (NT * BB)               // 384
#define FEAT_BLOCKS (2 * BB * TSPLIT * 2)  // 1024 (d-split 2)
#define TOT_BLOCKS (GCN_BLOCKS + FEAT_BLOCKS + 1)  // 1409 = 11*128 + 1

#define ALPHA_W 0.0005f
#define BETA_W 0.1f
#define MARGIN_W 100.0f
#define GCN_W 0.1f
#define EPS_V 1e-8f

// ws float offsets
#define WS_LOSS01 0
#define WS_N2ACT 16
#define WS_N2BKG 48
#define WS_GCNB 80
#define WS_S2 128          // 2048 floats
#define WS_CAND 4096       // 32*64*12*8 = 196608 floats
#define WS_COLSUM 200704   // 2*32*8*2048 = 1048576 floats

typedef __attribute__((ext_vector_type(8))) short bf16x8;
typedef __attribute__((ext_vector_type(4))) float f32x4;

// f32 -> bf16 round-to-nearest-even
__device__ __forceinline__ unsigned short f2bf(float f) {
  unsigned int u = __float_as_uint(f);
  return (unsigned short)((u + 0x7FFFu + ((u >> 16) & 1u)) >> 16);
}

// ---------------------------------------------------------------------------
// Mega kernel. Interleave: 1408 = 11*128; bx%11 in {0,1,2} -> gcn (384),
// {3..10} -> feat (1024), bx==1408 -> bce. Fine interleave mixes MFMA-bound
// gcn with HBM-bound feat on every CU/XCD.
// ---------------------------------------------------------------------------
__global__ __launch_bounds__(256, 6) void mega_kernel(
    const float* __restrict__ score_act, const float* __restrict__ score_bkg,
    const float* __restrict__ feat_act, const float* __restrict__ feat_bkg,
    const float* __restrict__ label, const float* __restrict__ nodes,
    const int* __restrict__ nlab, const int* __restrict__ sidx,
    float* __restrict__ ws) {
  int bx = blockIdx.x;
  int tid = threadIdx.x;
  int q11 = bx / 11, r11 = bx % 11;

  if (bx < TOT_BLOCKS - 1 && r11 < 3) {
    // ---------------- GCN tile: batch b, 64-m tile, bf16 MFMA ----------------
    int idx = q11 * 3 + r11;
    int b = idx / NT, tile = idx % NT;

    // LDS: bf16 tiles, 64 rows x 64 k each; rows = 128B = 8 16B-units,
    // XOR-swizzled by (row&7) on the 16B unit index.
    __shared__ __align__(16) unsigned short sAh[64 * 64];
    __shared__ __align__(16) unsigned short sBh[64 * 64];
    __shared__ float sS2[SS];
    __shared__ float sN2[MT];
    __shared__ int sSlab[SS];
    __shared__ int sMlab[MT];

    if (tid < SS) {
      sSlab[tid] = nlab[b * MM + sidx[b * SS + tid]];
    } else if (tid < SS + MT) {
      int ml = tid - SS;
      int m = tile * MT + ml;
      sMlab[ml] = (m < MM) ? nlab[b * MM + m] : -2;
    }

    // staging: thread -> row r = tid>>2 (both A-s-row and B-m-row), p = tid&3,
    // covering 8B-granules u = p+4j (j=0..3) of the 64-f32 chunk row.
    int r = tid >> 2, p = tid & 3;
    const float* aRow = nodes + ((size_t)b * MM + sidx[b * SS + r]) * DD;
    int mrow = tile * MT + r;
    bool bval = (mrow < MM);
    const float* bRow = nodes + ((size_t)b * MM + (bval ? mrow : 0)) * DD;

    int wslot[4];  // ushort index of the 8B granule in the swizzled row
#pragma unroll
    for (int j = 0; j < 4; ++j) {
      int u = p + 4 * j;
      wslot[j] = r * 64 + ((((u >> 1) ^ (r & 7)) << 1) + (u & 1)) * 4;
    }

    int lane = tid & 63, w = tid >> 6;
    int g = lane >> 4, c = lane & 15;

    float aSq = 0.f, bSq = 0.f;
    f32x4 acc[4];
#pragma unroll
    for (int f = 0; f < 4; ++f) acc[f] = (f32x4){0.f, 0.f, 0.f, 0.f};

    // prefetch chunk 0
    float4 pa[4], pb[4];
#pragma unroll
    for (int j = 0; j < 4; ++j) {
      int off = (p + 4 * j) * 4;
      pa[j] = *(const float4*)(aRow + off);
      pb[j] = *(const float4*)(bRow + off);
    }

    for (int ch = 0; ch < 32; ++ch) {
      __syncthreads();  // previous chunk's LDS reads done
#pragma unroll
      for (int j = 0; j < 4; ++j) {
        float4 v = pa[j];
        aSq += v.x * v.x + v.y * v.y + v.z * v.z + v.w * v.w;
        unsigned int lo = (unsigned int)f2bf(v.x) | ((unsigned int)f2bf(v.y) << 16);
        unsigned int hi = (unsigned int)f2bf(v.z) | ((unsigned int)f2bf(v.w) << 16);
        *(uint2*)&sAh[wslot[j]] = make_uint2(lo, hi);
        float4 t = pb[j];
        bSq += t.x * t.x + t.y * t.y + t.z * t.z + t.w * t.w;
        lo = (unsigned int)f2bf(t.x) | ((unsigned int)f2bf(t.y) << 16);
        hi = (unsigned int)f2bf(t.z) | ((unsigned int)f2bf(t.w) << 16);
        *(uint2*)&sBh[wslot[j]] = make_uint2(lo, hi);
      }
      __syncthreads();  // tile visible
      if (ch < 31) {    // issue next chunk's loads; latency hides under MFMA
        const float* ap = aRow + (ch + 1) * 64;
        const float* bp = bRow + (ch + 1) * 64;
#pragma unroll
        for (int j = 0; j < 4; ++j) {
          int off = (p + 4 * j) * 4;
          pa[j] = *(const float4*)(ap + off);
          pb[j] = *(const float4*)(bp + off);
        }
      }
      // compute: 2 k-steps of 32 over the 64-k chunk
#pragma unroll
      for (int kk = 0; kk < 2; ++kk) {
        int su = kk * 4 + g;
        int arow = w * 16 + c;
        bf16x8 af = *(const bf16x8*)&sAh[arow * 64 + (su ^ (arow & 7)) * 8];
#pragma unroll
        for (int f = 0; f < 4; ++f) {
          int brow = f * 16 + c;
          bf16x8 bfr = *(const bf16x8*)&sBh[brow * 64 + (su ^ (brow & 7)) * 8];
          acc[f] = __builtin_amdgcn_mfma_f32_16x16x32_bf16(af, bfr, acc[f], 0, 0, 0);
        }
      }
    }

    // exact-f32 row sums of squares: reduce across the 4 p-lanes per row
    aSq += __shfl_down(aSq, 2, 4);
    aSq += __shfl_down(aSq, 1, 4);
    bSq += __shfl_down(bSq, 2, 4);
    bSq += __shfl_down(bSq, 1, 4);
    if (p == 0) {
      sS2[r] = aSq;
      sN2[r] = bSq;
    }
    __syncthreads();

    if (tile == 0 && tid < SS) ws[WS_S2 + b * SS + tid] = sS2[tid];

    // selection: lane holds C[s][m] for s = w*16+g*4+reg, m_local = f*16+c
#pragma unroll
    for (int reg = 0; reg < 4; ++reg) {
      int s = w * 16 + g * 4 + reg;
      int slab = sSlab[s];
      float s2v = sS2[s];
      float posD = -3.4e38f, posC = 0.f, posN = 0.f;
      int posI = -1;
      float negD = 3.4e38f, negC = 0.f, negN = 0.f;
      int negI = -1;
#pragma unroll
      for (int f = 0; f < 4; ++f) {
        int ml = f * 16 + c;
        int lab = sMlab[ml];
        float cv = acc[f][reg];
        float n2 = sN2[ml];
        float d2 = fmaxf(s2v + n2 - 2.f * cv, 0.f);
        if (lab >= 0 && lab == slab && (posI < 0 || d2 > posD)) {
          posD = d2; posI = tile * MT + ml; posC = cv; posN = n2;
        }
        if (lab >= 0 && lab != slab && (negI < 0 || d2 < negD)) {
          negD = d2; negI = tile * MT + ml; negC = cv; negN = n2;
        }
      }
      // tuple reduce across the 16 c-lanes (quarter-wave), JAX tie-break
#pragma unroll
      for (int off = 8; off; off >>= 1) {
        float oD = __shfl_down(posD, off, 16);
        int oI = __shfl_down(posI, off, 16);
        float oC = __shfl_down(posC, off, 16);
        float oN = __shfl_down(posN, off, 16);
        bool take = (oI >= 0) &&
                    (posI < 0 || oD > posD || (oD == posD && oI < posI));
        if (take) { posD = oD; posI = oI; posC = oC; posN = oN; }
        oD = __shfl_down(negD, off, 16);
        oI = __shfl_down(negI, off, 16);
        oC = __shfl_down(negC, off, 16);
        oN = __shfl_down(negN, off, 16);
        take = (oI >= 0) &&
               (negI < 0 || oD < negD || (oD == negD && oI < negI));
        if (take) { negD = oD; negI = oI; negC = oC; negN = oN; }
      }
      if (c == 0) {
        size_t base = (((size_t)b * SS + s) * NT + tile) * 8;
        *(float4*)&ws[WS_CAND + base] =
            make_float4(posD, __int_as_float(posI), posC, posN);
        *(float4*)&ws[WS_CAND + base + 4] =
            make_float4(negD, __int_as_float(negI), negC, negN);
      }
    }
  } else if (bx < TOT_BLOCKS - 1) {
    // ------- feat column-sum partials (HBM-bound, d-split 2, unroll 8) -------
    int idx = q11 * 8 + (r11 - 3);   // 0..1023
    int tz = idx >> 9;               // 0: act, 1: bkg
    int rem = idx & 511;
    int fb = rem >> 4;               // batch
    int sub = rem & 15;
    int blk = sub >> 1;              // t-chunk 0..7
    int dh = sub & 1;                // d-half
    const float* feat = tz ? feat_bkg : feat_act;
    int t0 = blk * TCH;
    int t1 = t0 + TCH < TT ? t0 + TCH : TT;
    const float* bp = feat + (size_t)fb * TT * DD + dh * 1024 + tid * 4;
    float4 s0 = make_float4(0.f, 0.f, 0.f, 0.f);
#pragma unroll 8
    for (int t = t0; t < t1; ++t) {
      float4 v = *(const float4*)(bp + (size_t)t * DD);
      s0.x += v.x; s0.y += v.y; s0.z += v.z; s0.w += v.w;
    }
    float* cs = ws + WS_COLSUM +
                ((size_t)(tz * BB + fb) * TSPLIT + blk) * DD + dh * 1024 +
                tid * 4;
    *(float4*)cs = s0;
  } else {
    // ---------------- BCE losses ----------------
    float vc = 0.f, vb = 0.f;
    for (int i = tid; i < BB * CC; i += 256) {
      int b = i / CC, c = i % CC;
      float rs = 0.f;
      for (int k = 0; k < CC; ++k) rs += label[b * CC + k];
      float ln = label[b * CC + c] / rs;
      float pa = score_act[i];
      vc += ln * logf(pa) + (1.f - ln) * logf(1.f - pa);
      float pb = score_bkg[i];
      const float tb = 1.f / (float)CC;
      vb += tb * logf(pb) + (1.f - tb) * logf(1.f - pb);
    }
    for (int off = 32; off; off >>= 1) {
      vc += __shfl_down(vc, off, 64);
      vb += __shfl_down(vb, off, 64);
    }
    __shared__ float rc[4], rb[4];
    if ((tid & 63) == 0) {
      rc[tid >> 6] = vc;
      rb[tid >> 6] = vb;
    }
    __syncthreads();
    if (tid == 0) {
      ws[WS_LOSS01] = -(rc[0] + rc[1] + rc[2] + rc[3]) / (float)(BB * CC);
      ws[WS_LOSS01 + 1] = -(rb[0] + rb[1] + rb[2] + rb[3]) / (float)(BB * CC);
    }
  }
}

// ---------------------------------------------------------------------------
// Tail: [0,64) feat norm finalize | [64,96) gcn per-(b,s) combine.
// ---------------------------------------------------------------------------
__global__ __launch_bounds__(256) void tail_kernel(float* __restrict__ ws) {
  int bx = blockIdx.x, tid = threadIdx.x;
  if (bx < 64) {
    int tz = bx >> 5, fb = bx & 31;
    const float* cs = ws + WS_COLSUM + (size_t)(tz * BB + fb) * TSPLIT * DD;
    int d0 = tid * 8;
    float4 A0 = make_float4(0.f, 0.f, 0.f, 0.f);
    float4 A1 = make_float4(0.f, 0.f, 0.f, 0.f);
    for (int blk = 0; blk < TSPLIT; ++blk) {
      const float* pp = cs + blk * DD + d0;
      float4 u = *(const float4*)pp;
      float4 v = *(const float4*)(pp + 4);
      A0.x += u.x; A0.y += u.y; A0.z += u.z; A0.w += u.w;
      A1.x += v.x; A1.y += v.y; A1.z += v.z; A1.w += v.w;
    }
    const float inv = 1.f / (float)TT;
    float m0 = A0.x * inv, m1 = A0.y * inv, m2 = A0.z * inv, m3 = A0.w * inv;
    float m4 = A1.x * inv, m5 = A1.y * inv, m6 = A1.z * inv, m7 = A1.w * inv;
    float v = m0 * m0 + m1 * m1 + m2 * m2 + m3 * m3 +
              m4 * m4 + m5 * m5 + m6 * m6 + m7 * m7;
    for (int off = 32; off; off >>= 1) v += __shfl_down(v, off, 64);
    __shared__ float red[4];
    if ((tid & 63) == 0) red[tid >> 6] = v;
    __syncthreads();
    if (tid == 0)
      ws[(tz ? WS_N2BKG : WS_N2ACT) + fb] = red[0] + red[1] + red[2] + red[3];
  } else {
    int b = bx - 64;
    if (tid < SS) {
      const float* cb = ws + WS_CAND + ((size_t)b * SS + tid) * NT * 8;
      float posD = -3.4e38f, posC = 0.f, posN = 0.f;
      int posI = -1;
      float negD = 3.4e38f, negC = 0.f, negN = 0.f;
      int negI = -1;
      for (int t = 0; t < NT; ++t) {
        float4 pq = *(const float4*)&cb[t * 8];
        int oI = __float_as_int(pq.y);
        if (oI >= 0 && (posI < 0 || pq.x > posD || (pq.x == posD && oI < posI))) {
          posD = pq.x; posI = oI; posC = pq.z; posN = pq.w;
        }
        float4 qq = *(const float4*)&cb[t * 8 + 4];
        oI = __float_as_int(qq.y);
        if (oI >= 0 && (negI < 0 || qq.x < negD || (qq.x == negD && oI < negI))) {
          negD = qq.x; negI = oI; negC = qq.z; negN = qq.w;
        }
      }
      float snorm = sqrtf(ws[WS_S2 + b * SS + tid]);
      float sden = fmaxf(snorm, EPS_V);
      float pl = (posI >= 0) ? posC / (sden * fmaxf(sqrtf(posN), EPS_V)) : 0.f;
      float nl = (negI >= 0) ? negC / (sden * fmaxf(sqrtf(negN), EPS_V)) : 0.f;
      float v = pl + nl;
      for (int off = 32; off; off >>= 1) v += __shfl_down(v, off, 64);
      if (tid == 0) ws[WS_GCNB + b] = v;
    }
  }
}

// ---------------------------------------------------------------------------
// Final deterministic scalar combine.
// ---------------------------------------------------------------------------
__global__ void final_kernel(const float* __restrict__ ws,
                             float* __restrict__ out) {
  int tid = threadIdx.x;  // 64 threads
  float um = 0.f, g = 0.f;
  if (tid < BB) {
    float la = fmaxf(MARGIN_W - sqrtf(ws[WS_N2ACT + tid]), 0.f);
    float lb = sqrtf(ws[WS_N2BKG + tid]);
    um = (la + lb) * (la + lb);
    g = ws[WS_GCNB + tid];
  }
  for (int off = 32; off; off >>= 1) {
    um += __shfl_down(um, off, 64);
    g += __shfl_down(g, off, 64);
  }
  if (tid == 0)
    out[0] = ws[WS_LOSS01] + BETA_W * ws[WS_LOSS01 + 1] +
             ALPHA_W * (um / (float)BB) + GCN_W * g;
}

// ---------------------------------------------------------------------------
extern "C" void kernel_launch(void* const* d_in, const int* in_sizes, int n_in,
                              void* d_out, int out_size, void* d_ws,
                              size_t ws_size, hipStream_t stream) {
  const float* score_act = (const float*)d_in[0];
  const float* score_bkg = (const float*)d_in[1];
  const float* feat_act = (const float*)d_in[2];
  const float* feat_bkg = (const float*)d_in[3];
  const float* label = (const float*)d_in[4];
  // d_in[5] = gt, d_in[6] = cas: unused by the reference loss
  const float* nodes = (const float*)d_in[7];
  const int* nlab = (const int*)d_in[8];
  const int* sidx = (const int*)d_in[9];
  float* out = (float*)d_out;
  float* wsf = (float*)d_ws;

  mega_kernel<<<TOT_BLOCKS, 256, 0, stream>>>(
      score_act, score_bkg, feat_act, feat_bkg, label, nodes, nlab, sidx, wsf);
  tail_kernel<<<96, 256, 0, stream>>>(wsf);
  final_kernel<<<1, 64, 0, stream>>>(wsf, out);
}

// Round 5
// 154.860 us; speedup vs baseline: 1.3461x; 1.3461x over previous
//
#include <hip/hip_runtime.h>
#include <math.h>

// Problem constants (from reference setup_inputs)
#define BB 32
#define TT 750
#define DD 2048
#define CC 20
#define MM 750
#define SS 64
#define MT 64          // gcn m-tile
#define NT 12          // ceil(750/64)
#define TSPLIT 8       // feat t-split
#define TCH 94         // ceil(750/8)

#define GCN_BLOCKS (NT * BB)               // 384
#define FEAT_BLOCKS (2 * BB * TSPLIT * 2)  // 1024 (d-split 2)
#define TOT_BLOCKS (GCN_BLOCKS + FEAT_BLOCKS + 1)  // 1409 = 11*128 + 1

#define ALPHA_W 0.0005f
#define BETA_W 0.1f
#define MARGIN_W 100.0f
#define GCN_W 0.1f
#define EPS_V 1e-8f

// ws float offsets
#define WS_LOSS01 0
#define WS_N2ACT 16
#define WS_N2BKG 48
#define WS_GCNB 80
#define WS_S2 128          // 2048 floats
#define WS_CAND 4096       // 32*64*12*8 = 196608 floats
#define WS_COLSUM 200704   // 2*32*8*2048 = 1048576 floats

typedef __attribute__((ext_vector_type(8))) short bf16x8;
typedef __attribute__((ext_vector_type(4))) float f32x4;

// f32 -> bf16 round-to-nearest-even
__device__ __forceinline__ unsigned short f2bf(float f) {
  unsigned int u = __float_as_uint(f);
  return (unsigned short)((u + 0x7FFFu + ((u >> 16) & 1u)) >> 16);
}

// ---------------------------------------------------------------------------
// Mega kernel. Interleave: 1408 = 11*128; bx%11 in {0,1,2} -> gcn (384),
// {3..10} -> feat (1024), bx==1408 -> bce. Fine interleave mixes MFMA-bound
// gcn with HBM-bound feat on every CU/XCD.
// NOTE: min-waves spec must stay at 3 — (256,6) capped VGPRs at 40 and the
// gcn loop spilled to scratch (+31 MB HBM writes, 131->208 us regression).
// ---------------------------------------------------------------------------
__global__ __launch_bounds__(256, 3) void mega_kernel(
    const float* __restrict__ score_act, const float* __restrict__ score_bkg,
    const float* __restrict__ feat_act, const float* __restrict__ feat_bkg,
    const float* __restrict__ label, const float* __restrict__ nodes,
    const int* __restrict__ nlab, const int* __restrict__ sidx,
    float* __restrict__ ws) {
  int bx = blockIdx.x;
  int tid = threadIdx.x;
  int q11 = bx / 11, r11 = bx % 11;

  if (bx < TOT_BLOCKS - 1 && r11 < 3) {
    // ---------------- GCN tile: batch b, 64-m tile, bf16 MFMA ----------------
    int idx = q11 * 3 + r11;
    int b = idx / NT, tile = idx % NT;

    // LDS: bf16 tiles, 64 rows x 64 k each; rows = 128B = 8 16B-units,
    // XOR-swizzled by (row&7) on the 16B unit index.
    __shared__ __align__(16) unsigned short sAh[64 * 64];
    __shared__ __align__(16) unsigned short sBh[64 * 64];
    __shared__ float sS2[SS];
    __shared__ float sN2[MT];
    __shared__ int sSlab[SS];
    __shared__ int sMlab[MT];

    if (tid < SS) {
      sSlab[tid] = nlab[b * MM + sidx[b * SS + tid]];
    } else if (tid < SS + MT) {
      int ml = tid - SS;
      int m = tile * MT + ml;
      sMlab[ml] = (m < MM) ? nlab[b * MM + m] : -2;
    }

    // staging: thread -> row r = tid>>2 (both A-s-row and B-m-row), p = tid&3,
    // covering 8B-granules u = p+4j (j=0..3) of the 64-f32 chunk row.
    int r = tid >> 2, p = tid & 3;
    const float* aRow = nodes + ((size_t)b * MM + sidx[b * SS + r]) * DD;
    int mrow = tile * MT + r;
    bool bval = (mrow < MM);
    const float* bRow = nodes + ((size_t)b * MM + (bval ? mrow : 0)) * DD;

    int wslot[4];  // ushort index of the 8B granule in the swizzled row
#pragma unroll
    for (int j = 0; j < 4; ++j) {
      int u = p + 4 * j;
      wslot[j] = r * 64 + ((((u >> 1) ^ (r & 7)) << 1) + (u & 1)) * 4;
    }

    int lane = tid & 63, w = tid >> 6;
    int g = lane >> 4, c = lane & 15;

    float aSq = 0.f, bSq = 0.f;
    f32x4 acc[4];
#pragma unroll
    for (int f = 0; f < 4; ++f) acc[f] = (f32x4){0.f, 0.f, 0.f, 0.f};

    // prefetch chunk 0
    float4 pa[4], pb[4];
#pragma unroll
    for (int j = 0; j < 4; ++j) {
      int off = (p + 4 * j) * 4;
      pa[j] = *(const float4*)(aRow + off);
      pb[j] = *(const float4*)(bRow + off);
    }

    for (int ch = 0; ch < 32; ++ch) {
      __syncthreads();  // previous chunk's LDS reads done
#pragma unroll
      for (int j = 0; j < 4; ++j) {
        float4 v = pa[j];
        aSq += v.x * v.x + v.y * v.y + v.z * v.z + v.w * v.w;
        unsigned int lo = (unsigned int)f2bf(v.x) | ((unsigned int)f2bf(v.y) << 16);
        unsigned int hi = (unsigned int)f2bf(v.z) | ((unsigned int)f2bf(v.w) << 16);
        *(uint2*)&sAh[wslot[j]] = make_uint2(lo, hi);
        float4 t = pb[j];
        bSq += t.x * t.x + t.y * t.y + t.z * t.z + t.w * t.w;
        lo = (unsigned int)f2bf(t.x) | ((unsigned int)f2bf(t.y) << 16);
        hi = (unsigned int)f2bf(t.z) | ((unsigned int)f2bf(t.w) << 16);
        *(uint2*)&sBh[wslot[j]] = make_uint2(lo, hi);
      }
      __syncthreads();  // tile visible
      if (ch < 31) {    // issue next chunk's loads; latency hides under MFMA
        const float* ap = aRow + (ch + 1) * 64;
        const float* bp = bRow + (ch + 1) * 64;
#pragma unroll
        for (int j = 0; j < 4; ++j) {
          int off = (p + 4 * j) * 4;
          pa[j] = *(const float4*)(ap + off);
          pb[j] = *(const float4*)(bp + off);
        }
      }
      // compute: 2 k-steps of 32 over the 64-k chunk
#pragma unroll
      for (int kk = 0; kk < 2; ++kk) {
        int su = kk * 4 + g;
        int arow = w * 16 + c;
        bf16x8 af = *(const bf16x8*)&sAh[arow * 64 + (su ^ (arow & 7)) * 8];
#pragma unroll
        for (int f = 0; f < 4; ++f) {
          int brow = f * 16 + c;
          bf16x8 bfr = *(const bf16x8*)&sBh[brow * 64 + (su ^ (brow & 7)) * 8];
          acc[f] = __builtin_amdgcn_mfma_f32_16x16x32_bf16(af, bfr, acc[f], 0, 0, 0);
        }
      }
    }

    // exact-f32 row sums of squares: reduce across the 4 p-lanes per row
    aSq += __shfl_down(aSq, 2, 4);
    aSq += __shfl_down(aSq, 1, 4);
    bSq += __shfl_down(bSq, 2, 4);
    bSq += __shfl_down(bSq, 1, 4);
    if (p == 0) {
      sS2[r] = aSq;
      sN2[r] = bSq;
    }
    __syncthreads();

    if (tile == 0 && tid < SS) ws[WS_S2 + b * SS + tid] = sS2[tid];

    // selection: lane holds C[s][m] for s = w*16+g*4+reg, m_local = f*16+c
#pragma unroll
    for (int reg = 0; reg < 4; ++reg) {
      int s = w * 16 + g * 4 + reg;
      int slab = sSlab[s];
      float s2v = sS2[s];
      float posD = -3.4e38f, posC = 0.f, posN = 0.f;
      int posI = -1;
      float negD = 3.4e38f, negC = 0.f, negN = 0.f;
      int negI = -1;
#pragma unroll
      for (int f = 0; f < 4; ++f) {
        int ml = f * 16 + c;
        int lab = sMlab[ml];
        float cv = acc[f][reg];
        float n2 = sN2[ml];
        float d2 = fmaxf(s2v + n2 - 2.f * cv, 0.f);
        if (lab >= 0 && lab == slab && (posI < 0 || d2 > posD)) {
          posD = d2; posI = tile * MT + ml; posC = cv; posN = n2;
        }
        if (lab >= 0 && lab != slab && (negI < 0 || d2 < negD)) {
          negD = d2; negI = tile * MT + ml; negC = cv; negN = n2;
        }
      }
      // tuple reduce across the 16 c-lanes (quarter-wave), JAX tie-break
#pragma unroll
      for (int off = 8; off; off >>= 1) {
        float oD = __shfl_down(posD, off, 16);
        int oI = __shfl_down(posI, off, 16);
        float oC = __shfl_down(posC, off, 16);
        float oN = __shfl_down(posN, off, 16);
        bool take = (oI >= 0) &&
                    (posI < 0 || oD > posD || (oD == posD && oI < posI));
        if (take) { posD = oD; posI = oI; posC = oC; posN = oN; }
        oD = __shfl_down(negD, off, 16);
        oI = __shfl_down(negI, off, 16);
        oC = __shfl_down(negC, off, 16);
        oN = __shfl_down(negN, off, 16);
        take = (oI >= 0) &&
               (negI < 0 || oD < negD || (oD == negD && oI < negI));
        if (take) { negD = oD; negI = oI; negC = oC; negN = oN; }
      }
      if (c == 0) {
        size_t base = (((size_t)b * SS + s) * NT + tile) * 8;
        *(float4*)&ws[WS_CAND + base] =
            make_float4(posD, __int_as_float(posI), posC, posN);
        *(float4*)&ws[WS_CAND + base + 4] =
            make_float4(negD, __int_as_float(negI), negC, negN);
      }
    }
  } else if (bx < TOT_BLOCKS - 1) {
    // ------- feat column-sum partials (HBM-bound, d-split 2, unroll 8) -------
    int idx = q11 * 8 + (r11 - 3);   // 0..1023
    int tz = idx >> 9;               // 0: act, 1: bkg
    int rem = idx & 511;
    int fb = rem >> 4;               // batch
    int sub = rem & 15;
    int blk = sub >> 1;              // t-chunk 0..7
    int dh = sub & 1;                // d-half
    const float* feat = tz ? feat_bkg : feat_act;
    int t0 = blk * TCH;
    int t1 = t0 + TCH < TT ? t0 + TCH : TT;
    const float* bp = feat + (size_t)fb * TT * DD + dh * 1024 + tid * 4;
    float4 s0 = make_float4(0.f, 0.f, 0.f, 0.f);
#pragma unroll 8
    for (int t = t0; t < t1; ++t) {
      float4 v = *(const float4*)(bp + (size_t)t * DD);
      s0.x += v.x; s0.y += v.y; s0.z += v.z; s0.w += v.w;
    }
    float* cs = ws + WS_COLSUM +
                ((size_t)(tz * BB + fb) * TSPLIT + blk) * DD + dh * 1024 +
                tid * 4;
    *(float4*)cs = s0;
  } else {
    // ---------------- BCE losses ----------------
    float vc = 0.f, vb = 0.f;
    for (int i = tid; i < BB * CC; i += 256) {
      int b = i / CC, c = i % CC;
      float rs = 0.f;
      for (int k = 0; k < CC; ++k) rs += label[b * CC + k];
      float ln = label[b * CC + c] / rs;
      float pa = score_act[i];
      vc += ln * logf(pa) + (1.f - ln) * logf(1.f - pa);
      float pb = score_bkg[i];
      const float tb = 1.f / (float)CC;
      vb += tb * logf(pb) + (1.f - tb) * logf(1.f - pb);
    }
    for (int off = 32; off; off >>= 1) {
      vc += __shfl_down(vc, off, 64);
      vb += __shfl_down(vb, off, 64);
    }
    __shared__ float rc[4], rb[4];
    if ((tid & 63) == 0) {
      rc[tid >> 6] = vc;
      rb[tid >> 6] = vb;
    }
    __syncthreads();
    if (tid == 0) {
      ws[WS_LOSS01] = -(rc[0] + rc[1] + rc[2] + rc[3]) / (float)(BB * CC);
      ws[WS_LOSS01 + 1] = -(rb[0] + rb[1] + rb[2] + rb[3]) / (float)(BB * CC);
    }
  }
}

// ---------------------------------------------------------------------------
// Tail: [0,64) feat norm finalize | [64,96) gcn per-(b,s) combine.
// ---------------------------------------------------------------------------
__global__ __launch_bounds__(256) void tail_kernel(float* __restrict__ ws) {
  int bx = blockIdx.x, tid = threadIdx.x;
  if (bx < 64) {
    int tz = bx >> 5, fb = bx & 31;
    const float* cs = ws + WS_COLSUM + (size_t)(tz * BB + fb) * TSPLIT * DD;
    int d0 = tid * 8;
    float4 A0 = make_float4(0.f, 0.f, 0.f, 0.f);
    float4 A1 = make_float4(0.f, 0.f, 0.f, 0.f);
    for (int blk = 0; blk < TSPLIT; ++blk) {
      const float* pp = cs + blk * DD + d0;
      float4 u = *(const float4*)pp;
      float4 v = *(const float4*)(pp + 4);
      A0.x += u.x; A0.y += u.y; A0.z += u.z; A0.w += u.w;
      A1.x += v.x; A1.y += v.y; A1.z += v.z; A1.w += v.w;
    }
    const float inv = 1.f / (float)TT;
    float m0 = A0.x * inv, m1 = A0.y * inv, m2 = A0.z * inv, m3 = A0.w * inv;
    float m4 = A1.x * inv, m5 = A1.y * inv, m6 = A1.z * inv, m7 = A1.w * inv;
    float v = m0 * m0 + m1 * m1 + m2 * m2 + m3 * m3 +
              m4 * m4 + m5 * m5 + m6 * m6 + m7 * m7;
    for (int off = 32; off; off >>= 1) v += __shfl_down(v, off, 64);
    __shared__ float red[4];
    if ((tid & 63) == 0) red[tid >> 6] = v;
    __syncthreads();
    if (tid == 0)
      ws[(tz ? WS_N2BKG : WS_N2ACT) + fb] = red[0] + red[1] + red[2] + red[3];
  } else {
    int b = bx - 64;
    if (tid < SS) {
      const float* cb = ws + WS_CAND + ((size_t)b * SS + tid) * NT * 8;
      float posD = -3.4e38f, posC = 0.f, posN = 0.f;
      int posI = -1;
      float negD = 3.4e38f, negC = 0.f, negN = 0.f;
      int negI = -1;
      for (int t = 0; t < NT; ++t) {
        float4 pq = *(const float4*)&cb[t * 8];
        int oI = __float_as_int(pq.y);
        if (oI >= 0 && (posI < 0 || pq.x > posD || (pq.x == posD && oI < posI))) {
          posD = pq.x; posI = oI; posC = pq.z; posN = pq.w;
        }
        float4 qq = *(const float4*)&cb[t * 8 + 4];
        oI = __float_as_int(qq.y);
        if (oI >= 0 && (negI < 0 || qq.x < negD || (qq.x == negD && oI < negI))) {
          negD = qq.x; negI = oI; negC = qq.z; negN = qq.w;
        }
      }
      float snorm = sqrtf(ws[WS_S2 + b * SS + tid]);
      float sden = fmaxf(snorm, EPS_V);
      float pl = (posI >= 0) ? posC / (sden * fmaxf(sqrtf(posN), EPS_V)) : 0.f;
      float nl = (negI >= 0) ? negC / (sden * fmaxf(sqrtf(negN), EPS_V)) : 0.f;
      float v = pl + nl;
      for (int off = 32; off; off >>= 1) v += __shfl_down(v, off, 64);
      if (tid == 0) ws[WS_GCNB + b] = v;
    }
  }
}

// ---------------------------------------------------------------------------
// Final deterministic scalar combine.
// ---------------------------------------------------------------------------
__global__ void final_kernel(const float* __restrict__ ws,
                             float* __restrict__ out) {
  int tid = threadIdx.x;  // 64 threads
  float um = 0.f, g = 0.f;
  if (tid < BB) {
    float la = fmaxf(MARGIN_W - sqrtf(ws[WS_N2ACT + tid]), 0.f);
    float lb = sqrtf(ws[WS_N2BKG + tid]);
    um = (la + lb) * (la + lb);
    g = ws[WS_GCNB + tid];
  }
  for (int off = 32; off; off >>= 1) {
    um += __shfl_down(um, off, 64);
    g += __shfl_down(g, off, 64);
  }
  if (tid == 0)
    out[0] = ws[WS_LOSS01] + BETA_W * ws[WS_LOSS01 + 1] +
             ALPHA_W * (um / (float)BB) + GCN_W * g;
}

// ---------------------------------------------------------------------------
extern "C" void kernel_launch(void* const* d_in, const int* in_sizes, int n_in,
                              void* d_out, int out_size, void* d_ws,
                              size_t ws_size, hipStream_t stream) {
  const float* score_act = (const float*)d_in[0];
  const float* score_bkg = (const float*)d_in[1];
  const float* feat_act = (const float*)d_in[2];
  const float* feat_bkg = (const float*)d_in[3];
  const float* label = (const float*)d_in[4];
  // d_in[5] = gt, d_in[6] = cas: unused by the reference loss
  const float* nodes = (const float*)d_in[7];
  const int* nlab = (const int*)d_in[8];
  const int* sidx = (const int*)d_in[9];
  float* out = (float*)d_out;
  float* wsf = (float*)d_ws;

  mega_kernel<<<TOT_BLOCKS, 256, 0, stream>>>(
      score_act, score_bkg, feat_act, feat_bkg, label, nodes, nlab, sidx, wsf);
  tail_kernel<<<96, 256, 0, stream>>>(wsf);
  final_kernel<<<1, 64, 0, stream>>>(wsf, out);
}

// Round 6
// 119.940 us; speedup vs baseline: 1.7380x; 1.2911x over previous
//
#include <hip/hip_runtime.h>
#include <math.h>

// Problem constants (from reference setup_inputs)
#define BB 32
#define TT 750
#define DD 2048
#define CC 20
#define MM 750
#define SS 64
#define MT 64          // gcn m-tile
#define NT 12          // ceil(750/64)
#define TSPLIT 8       // feat t-split
#define TCH 94         // ceil(750/8)

#define GCN_BLOCKS (NT * BB)            // 384
#define FEAT_BLOCKS (2 * BB * TSPLIT)   // 512
#define TOT_BLOCKS (GCN_BLOCKS + FEAT_BLOCKS + 1)  // 897 = 7*128 + 1

#define ALPHA_W 0.0005f
#define BETA_W 0.1f
#define MARGIN_W 100.0f
#define GCN_W 0.1f
#define EPS_V 1e-8f

// ws float offsets
#define WS_LOSS01 0
#define WS_N2ACT 16
#define WS_N2BKG 48
#define WS_GCNB 80
#define WS_S2 128          // 2048 floats
#define WS_CAND 4096       // 32*64*12*8 = 196608 floats
#define WS_COLSUM 200704   // 2*32*8*2048 = 1048576 floats

typedef __attribute__((ext_vector_type(8))) short bf16x8;
typedef __attribute__((ext_vector_type(4))) float f32x4;

// f32 -> bf16 round-to-nearest-even
__device__ __forceinline__ unsigned short f2bf(float f) {
  unsigned int u = __float_as_uint(f);
  return (unsigned short)((u + 0x7FFFu + ((u >> 16) & 1u)) >> 16);
}

// ---------------------------------------------------------------------------
// Mega kernel. Role interleave: id%7 in {0,1,2} -> gcn (384), {3..6} -> feat
// (512), id==896 -> bce. Fine interleave mixes MFMA-bound gcn with HBM-bound
// feat on every CU/XCD.
// NOTE: min-waves spec must stay at 3 — (256,6) capped VGPRs at 40 and the
// gcn loop spilled to scratch (+31 MB HBM writes, 131->208 us regression).
// NOTE: feat d-split + pragma-unroll-8 regressed (131->155 us, HBM 1.92->1.77
// TB/s) — it halved per-wave loads/iter. Keep 2 rows x 2 halves = 4 loads/iter.
// ---------------------------------------------------------------------------
__global__ __launch_bounds__(256, 3) void mega_kernel(
    const float* __restrict__ score_act, const float* __restrict__ score_bkg,
    const float* __restrict__ feat_act, const float* __restrict__ feat_bkg,
    const float* __restrict__ label, const float* __restrict__ nodes,
    const int* __restrict__ nlab, const int* __restrict__ sidx,
    float* __restrict__ ws) {
  int bx = blockIdx.x;
  int tid = threadIdx.x;
  int q7 = bx / 7, r7 = bx % 7;

  if (bx < TOT_BLOCKS - 1 && r7 < 3) {
    // ---------------- GCN tile: batch b, 64-m tile, bf16 MFMA ----------------
    int idx = q7 * 3 + r7;
    int b = idx / NT, tile = idx % NT;

    // LDS: bf16 tiles, 64 rows x 64 k each; rows = 128B = 8 16B-units,
    // XOR-swizzled by (row&7) on the 16B unit index.
    __shared__ __align__(16) unsigned short sAh[64 * 64];
    __shared__ __align__(16) unsigned short sBh[64 * 64];
    __shared__ float sS2[SS];
    __shared__ float sN2[MT];
    __shared__ int sSlab[SS];
    __shared__ int sMlab[MT];

    if (tid < SS) {
      sSlab[tid] = nlab[b * MM + sidx[b * SS + tid]];
    } else if (tid < SS + MT) {
      int ml = tid - SS;
      int m = tile * MT + ml;
      sMlab[ml] = (m < MM) ? nlab[b * MM + m] : -2;
    }

    // staging: thread -> row r = tid>>2 (both A-s-row and B-m-row), p = tid&3,
    // covering 8B-granules u = p+4j (j=0..3) of the 64-f32 chunk row.
    int r = tid >> 2, p = tid & 3;
    const float* aRow = nodes + ((size_t)b * MM + sidx[b * SS + r]) * DD;
    int mrow = tile * MT + r;
    bool bval = (mrow < MM);
    const float* bRow = nodes + ((size_t)b * MM + (bval ? mrow : 0)) * DD;

    int wslot[4];  // ushort index of the 8B granule in the swizzled row
#pragma unroll
    for (int j = 0; j < 4; ++j) {
      int u = p + 4 * j;
      wslot[j] = r * 64 + ((((u >> 1) ^ (r & 7)) << 1) + (u & 1)) * 4;
    }

    int lane = tid & 63, w = tid >> 6;
    int g = lane >> 4, c = lane & 15;

    float aSq = 0.f, bSq = 0.f;
    f32x4 acc[4];
#pragma unroll
    for (int f = 0; f < 4; ++f) acc[f] = (f32x4){0.f, 0.f, 0.f, 0.f};

    // prefetch chunk 0
    float4 pa[4], pb[4];
#pragma unroll
    for (int j = 0; j < 4; ++j) {
      int off = (p + 4 * j) * 4;
      pa[j] = *(const float4*)(aRow + off);
      pb[j] = *(const float4*)(bRow + off);
    }

    for (int ch = 0; ch < 32; ++ch) {
      __syncthreads();  // previous chunk's LDS reads done
#pragma unroll
      for (int j = 0; j < 4; ++j) {
        float4 v = pa[j];
        aSq += v.x * v.x + v.y * v.y + v.z * v.z + v.w * v.w;
        unsigned int lo = (unsigned int)f2bf(v.x) | ((unsigned int)f2bf(v.y) << 16);
        unsigned int hi = (unsigned int)f2bf(v.z) | ((unsigned int)f2bf(v.w) << 16);
        *(uint2*)&sAh[wslot[j]] = make_uint2(lo, hi);
        float4 t = pb[j];
        bSq += t.x * t.x + t.y * t.y + t.z * t.z + t.w * t.w;
        lo = (unsigned int)f2bf(t.x) | ((unsigned int)f2bf(t.y) << 16);
        hi = (unsigned int)f2bf(t.z) | ((unsigned int)f2bf(t.w) << 16);
        *(uint2*)&sBh[wslot[j]] = make_uint2(lo, hi);
      }
      __syncthreads();  // tile visible
      if (ch < 31) {    // issue next chunk's loads; latency hides under MFMA
        const float* ap = aRow + (ch + 1) * 64;
        const float* bp = bRow + (ch + 1) * 64;
#pragma unroll
        for (int j = 0; j < 4; ++j) {
          int off = (p + 4 * j) * 4;
          pa[j] = *(const float4*)(ap + off);
          pb[j] = *(const float4*)(bp + off);
        }
      }
      // compute: 2 k-steps of 32 over the 64-k chunk
#pragma unroll
      for (int kk = 0; kk < 2; ++kk) {
        int su = kk * 4 + g;
        int arow = w * 16 + c;
        bf16x8 af = *(const bf16x8*)&sAh[arow * 64 + (su ^ (arow & 7)) * 8];
#pragma unroll
        for (int f = 0; f < 4; ++f) {
          int brow = f * 16 + c;
          bf16x8 bfr = *(const bf16x8*)&sBh[brow * 64 + (su ^ (brow & 7)) * 8];
          acc[f] = __builtin_amdgcn_mfma_f32_16x16x32_bf16(af, bfr, acc[f], 0, 0, 0);
        }
      }
    }

    // exact-f32 row sums of squares: reduce across the 4 p-lanes per row
    aSq += __shfl_down(aSq, 2, 4);
    aSq += __shfl_down(aSq, 1, 4);
    bSq += __shfl_down(bSq, 2, 4);
    bSq += __shfl_down(bSq, 1, 4);
    if (p == 0) {
      sS2[r] = aSq;
      sN2[r] = bSq;
    }
    __syncthreads();

    if (tile == 0 && tid < SS) ws[WS_S2 + b * SS + tid] = sS2[tid];

    // selection: lane holds C[s][m] for s = w*16+g*4+reg, m_local = f*16+c
#pragma unroll
    for (int reg = 0; reg < 4; ++reg) {
      int s = w * 16 + g * 4 + reg;
      int slab = sSlab[s];
      float s2v = sS2[s];
      float posD = -3.4e38f, posC = 0.f, posN = 0.f;
      int posI = -1;
      float negD = 3.4e38f, negC = 0.f, negN = 0.f;
      int negI = -1;
#pragma unroll
      for (int f = 0; f < 4; ++f) {
        int ml = f * 16 + c;
        int lab = sMlab[ml];
        float cv = acc[f][reg];
        float n2 = sN2[ml];
        float d2 = fmaxf(s2v + n2 - 2.f * cv, 0.f);
        if (lab >= 0 && lab == slab && (posI < 0 || d2 > posD)) {
          posD = d2; posI = tile * MT + ml; posC = cv; posN = n2;
        }
        if (lab >= 0 && lab != slab && (negI < 0 || d2 < negD)) {
          negD = d2; negI = tile * MT + ml; negC = cv; negN = n2;
        }
      }
      // tuple reduce across the 16 c-lanes (quarter-wave), JAX tie-break
#pragma unroll
      for (int off = 8; off; off >>= 1) {
        float oD = __shfl_down(posD, off, 16);
        int oI = __shfl_down(posI, off, 16);
        float oC = __shfl_down(posC, off, 16);
        float oN = __shfl_down(posN, off, 16);
        bool take = (oI >= 0) &&
                    (posI < 0 || oD > posD || (oD == posD && oI < posI));
        if (take) { posD = oD; posI = oI; posC = oC; posN = oN; }
        oD = __shfl_down(negD, off, 16);
        oI = __shfl_down(negI, off, 16);
        oC = __shfl_down(negC, off, 16);
        oN = __shfl_down(negN, off, 16);
        take = (oI >= 0) &&
               (negI < 0 || oD < negD || (oD == negD && oI < negI));
        if (take) { negD = oD; negI = oI; negC = oC; negN = oN; }
      }
      if (c == 0) {
        size_t base = (((size_t)b * SS + s) * NT + tile) * 8;
        *(float4*)&ws[WS_CAND + base] =
            make_float4(posD, __int_as_float(posI), posC, posN);
        *(float4*)&ws[WS_CAND + base + 4] =
            make_float4(negD, __int_as_float(negI), negC, negN);
      }
    }
  } else if (bx < TOT_BLOCKS - 1) {
    // ---- feat column-sum partials (HBM-bound, 2 rows x 2 halves per iter) ----
    int idx = q7 * 4 + (r7 - 3);
    int tz = idx >> 8;   // 0: act, 1: bkg
    int rem = idx & 255;
    int fb = rem >> 3;   // batch
    int blk = rem & 7;   // t-chunk
    const float* feat = tz ? feat_bkg : feat_act;
    int t0 = blk * TCH;
    int t1 = t0 + TCH < TT ? t0 + TCH : TT;  // trip = 94 or 92 -> always even
    const float* bp = feat + (size_t)fb * TT * DD + tid * 4;
    f32x4 s00 = {0.f, 0.f, 0.f, 0.f}, s01 = {0.f, 0.f, 0.f, 0.f};
    f32x4 s10 = {0.f, 0.f, 0.f, 0.f}, s11 = {0.f, 0.f, 0.f, 0.f};
    for (int t = t0; t < t1; t += 2) {
      const f32x4* p0 = (const f32x4*)(bp + (size_t)t * DD);
      const f32x4* p1 = (const f32x4*)(bp + (size_t)(t + 1) * DD);
      f32x4 v00 = __builtin_nontemporal_load(p0);        // no reuse: keep L2
      f32x4 v01 = __builtin_nontemporal_load(p0 + 256);  // clean for gcn nodes
      f32x4 v10 = __builtin_nontemporal_load(p1);
      f32x4 v11 = __builtin_nontemporal_load(p1 + 256);
      s00 += v00;
      s01 += v01;
      s10 += v10;
      s11 += v11;
    }
    f32x4 r0 = s00 + s10;
    f32x4 r1 = s01 + s11;
    float* cs = ws + WS_COLSUM +
                ((size_t)(tz * BB + fb) * TSPLIT + blk) * DD + tid * 4;
    *(f32x4*)cs = r0;
    *(f32x4*)(cs + 1024) = r1;
  } else {
    // ---------------- BCE losses ----------------
    float vc = 0.f, vb = 0.f;
    for (int i = tid; i < BB * CC; i += 256) {
      int b = i / CC, c = i % CC;
      float rs = 0.f;
      for (int k = 0; k < CC; ++k) rs += label[b * CC + k];
      float ln = label[b * CC + c] / rs;
      float pa = score_act[i];
      vc += ln * logf(pa) + (1.f - ln) * logf(1.f - pa);
      float pb = score_bkg[i];
      const float tb = 1.f / (float)CC;
      vb += tb * logf(pb) + (1.f - tb) * logf(1.f - pb);
    }
    for (int off = 32; off; off >>= 1) {
      vc += __shfl_down(vc, off, 64);
      vb += __shfl_down(vb, off, 64);
    }
    __shared__ float rc[4], rb[4];
    if ((tid & 63) == 0) {
      rc[tid >> 6] = vc;
      rb[tid >> 6] = vb;
    }
    __syncthreads();
    if (tid == 0) {
      ws[WS_LOSS01] = -(rc[0] + rc[1] + rc[2] + rc[3]) / (float)(BB * CC);
      ws[WS_LOSS01 + 1] = -(rb[0] + rb[1] + rb[2] + rb[3]) / (float)(BB * CC);
    }
  }
}

// ---------------------------------------------------------------------------
// Tail: [0,64) feat norm finalize | [64,96) gcn per-(b,s) combine.
// ---------------------------------------------------------------------------
__global__ __launch_bounds__(256) void tail_kernel(float* __restrict__ ws) {
  int bx = blockIdx.x, tid = threadIdx.x;
  if (bx < 64) {
    int tz = bx >> 5, fb = bx & 31;
    const float* cs = ws + WS_COLSUM + (size_t)(tz * BB + fb) * TSPLIT * DD;
    int d0 = tid * 8;
    float4 A0 = make_float4(0.f, 0.f, 0.f, 0.f);
    float4 A1 = make_float4(0.f, 0.f, 0.f, 0.f);
    for (int blk = 0; blk < TSPLIT; ++blk) {
      const float* pp = cs + blk * DD + d0;
      float4 u = *(const float4*)pp;
      float4 v = *(const float4*)(pp + 4);
      A0.x += u.x; A0.y += u.y; A0.z += u.z; A0.w += u.w;
      A1.x += v.x; A1.y += v.y; A1.z += v.z; A1.w += v.w;
    }
    const float inv = 1.f / (float)TT;
    float m0 = A0.x * inv, m1 = A0.y * inv, m2 = A0.z * inv, m3 = A0.w * inv;
    float m4 = A1.x * inv, m5 = A1.y * inv, m6 = A1.z * inv, m7 = A1.w * inv;
    float v = m0 * m0 + m1 * m1 + m2 * m2 + m3 * m3 +
              m4 * m4 + m5 * m5 + m6 * m6 + m7 * m7;
    for (int off = 32; off; off >>= 1) v += __shfl_down(v, off, 64);
    __shared__ float red[4];
    if ((tid & 63) == 0) red[tid >> 6] = v;
    __syncthreads();
    if (tid == 0)
      ws[(tz ? WS_N2BKG : WS_N2ACT) + fb] = red[0] + red[1] + red[2] + red[3];
  } else {
    int b = bx - 64;
    if (tid < SS) {
      const float* cb = ws + WS_CAND + ((size_t)b * SS + tid) * NT * 8;
      float posD = -3.4e38f, posC = 0.f, posN = 0.f;
      int posI = -1;
      float negD = 3.4e38f, negC = 0.f, negN = 0.f;
      int negI = -1;
      for (int t = 0; t < NT; ++t) {
        float4 pq = *(const float4*)&cb[t * 8];
        int oI = __float_as_int(pq.y);
        if (oI >= 0 && (posI < 0 || pq.x > posD || (pq.x == posD && oI < posI))) {
          posD = pq.x; posI = oI; posC = pq.z; posN = pq.w;
        }
        float4 qq = *(const float4*)&cb[t * 8 + 4];
        oI = __float_as_int(qq.y);
        if (oI >= 0 && (negI < 0 || qq.x < negD || (qq.x == negD && oI < negI))) {
          negD = qq.x; negI = oI; negC = qq.z; negN = qq.w;
        }
      }
      float snorm = sqrtf(ws[WS_S2 + b * SS + tid]);
      float sden = fmaxf(snorm, EPS_V);
      float pl = (posI >= 0) ? posC / (sden * fmaxf(sqrtf(posN), EPS_V)) : 0.f;
      float nl = (negI >= 0) ? negC / (sden * fmaxf(sqrtf(negN), EPS_V)) : 0.f;
      float v = pl + nl;
      for (int off = 32; off; off >>= 1) v += __shfl_down(v, off, 64);
      if (tid == 0) ws[WS_GCNB + b] = v;
    }
  }
}

// ---------------------------------------------------------------------------
// Final deterministic scalar combine.
// ---------------------------------------------------------------------------
__global__ void final_kernel(const float* __restrict__ ws,
                             float* __restrict__ out) {
  int tid = threadIdx.x;  // 64 threads
  float um = 0.f, g = 0.f;
  if (tid < BB) {
    float la = fmaxf(MARGIN_W - sqrtf(ws[WS_N2ACT + tid]), 0.f);
    float lb = sqrtf(ws[WS_N2BKG + tid]);
    um = (la + lb) * (la + lb);
    g = ws[WS_GCNB + tid];
  }
  for (int off = 32; off; off >>= 1) {
    um += __shfl_down(um, off, 64);
    g += __shfl_down(g, off, 64);
  }
  if (tid == 0)
    out[0] = ws[WS_LOSS01] + BETA_W * ws[WS_LOSS01 + 1] +
             ALPHA_W * (um / (float)BB) + GCN_W * g;
}

// ---------------------------------------------------------------------------
extern "C" void kernel_launch(void* const* d_in, const int* in_sizes, int n_in,
                              void* d_out, int out_size, void* d_ws,
                              size_t ws_size, hipStream_t stream) {
  const float* score_act = (const float*)d_in[0];
  const float* score_bkg = (const float*)d_in[1];
  const float* feat_act = (const float*)d_in[2];
  const float* feat_bkg = (const float*)d_in[3];
  const float* label = (const float*)d_in[4];
  // d_in[5] = gt, d_in[6] = cas: unused by the reference loss
  const float* nodes = (const float*)d_in[7];
  const int* nlab = (const int*)d_in[8];
  const int* sidx = (const int*)d_in[9];
  float* out = (float*)d_out;
  float* wsf = (float*)d_ws;

  mega_kernel<<<TOT_BLOCKS, 256, 0, stream>>>(
      score_act, score_bkg, feat_act, feat_bkg, label, nodes, nlab, sidx, wsf);
  tail_kernel<<<96, 256, 0, stream>>>(wsf);
  final_kernel<<<1, 64, 0, stream>>>(wsf, out);
}